// Round 1
// baseline (256.839 us; speedup 1.0000x reference)
//
#include <hip/hip_runtime.h>
#include <hip/hip_bf16.h>
#include <math.h>

// Problem constants (from reference): B=32, N=8192, D=128, fp32.
#define B 32
#define NROWS 8192
#define D 128
#define CHUNK 512                 // rows per block in K1
#define NCHUNK (NROWS / CHUNK)    // 16 chunks per batch

// ---------------------------------------------------------------------------
// K1: per (batch, chunk) block. 256 threads = 4 waves. Each wave handles one
// row at a time: lane holds float2 of the row (64*2 = 128 = D), dot with q,
// butterfly-reduce across the wave, then online-softmax accumulate so values
// is read from HBM exactly ONCE. Raw scores are written (coalesced) into the
// attn region of d_out, which K3 later finalizes in place.
// ---------------------------------------------------------------------------
__global__ __launch_bounds__(256) void attend_k1(
    const float* __restrict__ q,        // [B, D]
    const float* __restrict__ v,        // [B, N, D]
    float* __restrict__ out_scores,     // d_out attn region [B, N] (raw scores for now)
    float* __restrict__ part_m,         // [B*NCHUNK]
    float* __restrict__ part_l,         // [B*NCHUNK]
    float* __restrict__ part_o)         // [B*NCHUNK, D]
{
    __shared__ float s_lds[CHUNK];
    __shared__ float wm[4], wl[4];
    __shared__ float wo[4][D];

    const int b    = blockIdx.x >> 4;      // / NCHUNK
    const int c    = blockIdx.x & (NCHUNK - 1);
    const int n0   = c * CHUNK;
    const int tid  = threadIdx.x;
    const int w    = tid >> 6;             // wave id 0..3
    const int lane = tid & 63;

    const float2 q2 = ((const float2*)(q + b * D))[lane];
    const float2* vb = (const float2*)(v + ((size_t)b * NROWS) * D);

    float m = -INFINITY, l = 0.f;
    float2 acc = make_float2(0.f, 0.f);

    #pragma unroll 4
    for (int i = 0; i < CHUNK / 4; ++i) {
        const int n = n0 + w + 4 * i;
        const float2 v2 = vb[(size_t)n * (D / 2) + lane];
        float p = v2.x * q2.x + v2.y * q2.y;
        // butterfly sum across 64 lanes -> all lanes hold s
        #pragma unroll
        for (int off = 32; off > 0; off >>= 1)
            p += __shfl_xor(p, off, 64);
        const float s = p;
        if (lane == 0) s_lds[w + 4 * i] = s;

        if (s > m) {                        // rescale running state
            const float r = __expf(m - s);  // exp(-inf)=0 on first hit
            l *= r; acc.x *= r; acc.y *= r;
            m = s;
        }
        const float e = __expf(s - m);
        l += e;
        acc.x += e * v2.x;
        acc.y += e * v2.y;
    }

    if (lane == 0) { wm[w] = m; wl[w] = l; }
    wo[w][2 * lane]     = acc.x;
    wo[w][2 * lane + 1] = acc.y;
    __syncthreads();

    // coalesced raw-score write (512 floats by 256 threads)
    {
        float* dst = out_scores + (size_t)b * NROWS + n0;
        dst[tid]       = s_lds[tid];
        dst[tid + 256] = s_lds[tid + 256];
    }

    // combine the 4 waves' partials -> one chunk partial
    if (tid < D) {
        const float M = fmaxf(fmaxf(wm[0], wm[1]), fmaxf(wm[2], wm[3]));
        const float r0 = __expf(wm[0] - M);
        const float r1 = __expf(wm[1] - M);
        const float r2 = __expf(wm[2] - M);
        const float r3 = __expf(wm[3] - M);
        const float o = wo[0][tid] * r0 + wo[1][tid] * r1 +
                        wo[2][tid] * r2 + wo[3][tid] * r3;
        const int cid = blockIdx.x;
        part_o[(size_t)cid * D + tid] = o;
        if (tid == 0) {
            part_m[cid] = M;
            part_l[cid] = wl[0] * r0 + wl[1] * r1 + wl[2] * r2 + wl[3] * r3;
        }
    }
}

// ---------------------------------------------------------------------------
// K2: one block per batch (128 threads = one per output dim). Combine the 16
// chunk partials -> global max M, denom L, write context, stash M and 1/L.
// ---------------------------------------------------------------------------
__global__ __launch_bounds__(128) void attend_k2(
    const float* __restrict__ part_m,
    const float* __restrict__ part_l,
    const float* __restrict__ part_o,
    float* __restrict__ out_ctx,        // d_out + B*N, [B, D]
    float* __restrict__ bM,
    float* __restrict__ bInvL)
{
    const int b = blockIdx.x;
    const int d = threadIdx.x;
    __shared__ float sm[NCHUNK], sl[NCHUNK];
    if (d < NCHUNK) {
        sm[d] = part_m[b * NCHUNK + d];
        sl[d] = part_l[b * NCHUNK + d];
    }
    __syncthreads();

    float M = -INFINITY;
    #pragma unroll
    for (int c = 0; c < NCHUNK; ++c) M = fmaxf(M, sm[c]);

    float L = 0.f, o = 0.f;
    #pragma unroll
    for (int c = 0; c < NCHUNK; ++c) {
        const float r = __expf(sm[c] - M);
        L += sl[c] * r;
        o += part_o[(size_t)(b * NCHUNK + c) * D + d] * r;
    }
    out_ctx[b * D + d] = o / L;
    if (d == 0) { bM[b] = M; bInvL[b] = 1.0f / L; }
}

// ---------------------------------------------------------------------------
// K3: finalize attn in place: attn = exp(s - M) / L.
// ---------------------------------------------------------------------------
__global__ __launch_bounds__(256) void attend_k3(
    float* __restrict__ attn,           // d_out, [B, N] (holds raw scores)
    const float* __restrict__ bM,
    const float* __restrict__ bInvL)
{
    const int idx = blockIdx.x * 256 + threadIdx.x;
    const int b   = idx >> 13;          // / NROWS
    const float s = attn[idx];
    attn[idx] = __expf(s - bM[b]) * bInvL[b];
}

extern "C" void kernel_launch(void* const* d_in, const int* in_sizes, int n_in,
                              void* d_out, int out_size, void* d_ws, size_t ws_size,
                              hipStream_t stream) {
    const float* q = (const float*)d_in[0];   // [B,1,D]
    const float* v = (const float*)d_in[1];   // [B,N,D]
    float* out = (float*)d_out;               // attn [B*N] then context [B*D]

    // workspace layout (floats):
    //   part_m [B*NCHUNK] | part_l [B*NCHUNK] | part_o [B*NCHUNK*D] | bM [B] | bInvL [B]
    float* ws      = (float*)d_ws;
    float* part_m  = ws;
    float* part_l  = part_m + B * NCHUNK;
    float* part_o  = part_l + B * NCHUNK;
    float* bM      = part_o + (size_t)B * NCHUNK * D;
    float* bInvL   = bM + B;

    attend_k1<<<B * NCHUNK, 256, 0, stream>>>(q, v, out, part_m, part_l, part_o);
    attend_k2<<<B, 128, 0, stream>>>(part_m, part_l, part_o, out + (size_t)B * NROWS, bM, bInvL);
    attend_k3<<<(B * NROWS) / 256, 256, 0, stream>>>(out, bM, bInvL);
}

// Round 2
// 196.317 us; speedup vs baseline: 1.3083x; 1.3083x over previous
//
#include <hip/hip_runtime.h>
#include <hip/hip_bf16.h>
#include <math.h>

// Problem constants: B=32, N=8192, D=128, fp32.
#define B 32
#define NROWS 8192
#define D 128
#define CHUNK 256                 // rows per block in K1
#define NCHUNK (NROWS / CHUNK)    // 32 chunks per batch
#define RPW (CHUNK / 4)           // rows per wave = 64
#define ITER (RPW / 2)            // 2 rows per iteration = 32 iters

// ---------------------------------------------------------------------------
// K1: per (batch, chunk) block, 256 threads = 4 waves, each wave owns 64
// contiguous rows. Per iteration one float4 load instruction covers TWO rows
// (lanes 0-31 = row 2i, lanes 32-63 = row 2i+1). Score reduce = 5 butterfly
// shfl steps confined to 32-lane halves; online-softmax accumulator lives in
// the LOAD layout (lane owns d = 4*(lane&31)..+3 for its half's rows), so the
// accumulate path has zero cross-lane ops. One 6-shfl half-combine per wave
// at the end. values is read from HBM exactly once.
// ---------------------------------------------------------------------------
__global__ __launch_bounds__(256) void attend_k1(
    const float* __restrict__ q,        // [B, D]
    const float* __restrict__ v,        // [B, N, D]
    float* __restrict__ out_scores,     // d_out attn region [B, N] (raw scores)
    float* __restrict__ part_m,         // [B*NCHUNK]
    float* __restrict__ part_l,         // [B*NCHUNK]
    float* __restrict__ part_o)         // [B*NCHUNK, D]
{
    __shared__ float s_sc[CHUNK];       // raw scores for this chunk
    __shared__ float wm[4], wl[4];
    __shared__ float wo[4 * D];

    const int b    = blockIdx.x >> 5;          // / NCHUNK
    const int c    = blockIdx.x & (NCHUNK - 1);
    const int n0   = c * CHUNK;
    const int tid  = threadIdx.x;
    const int w    = tid >> 6;                 // wave 0..3
    const int lane = tid & 63;
    const int half = lane >> 5;                // 0: even row, 1: odd row
    const int l32  = lane & 31;

    const float4 q4 = ((const float4*)(q + b * D))[l32];
    const float4* vb = (const float4*)(v + ((size_t)b * NROWS + n0 + w * RPW) * D);

    float m = -INFINITY, l = 0.f;
    float4 acc = make_float4(0.f, 0.f, 0.f, 0.f);

    #pragma unroll 4
    for (int i = 0; i < ITER; ++i) {
        // flat float4 index i*64+lane -> row_local = 2i+half, d-quad = l32
        const float4 v4 = vb[i * 64 + lane];
        float p = v4.x * q4.x + v4.y * q4.y + v4.z * q4.z + v4.w * q4.w;
        // 5-step butterfly within each 32-lane half (masks < 32 never cross)
        p += __shfl_xor(p, 16, 64);
        p += __shfl_xor(p, 8, 64);
        p += __shfl_xor(p, 4, 64);
        p += __shfl_xor(p, 2, 64);
        p += __shfl_xor(p, 1, 64);
        const float s = p;                      // score of row 2i+half
        if (l32 == 0) s_sc[w * RPW + 2 * i + half] = s;

        // branchless online softmax (per-half state, uniform within half)
        const float mn = fmaxf(m, s);
        const float f  = __expf(m - mn);        // ==1 unless new max
        const float e  = __expf(s - mn);
        l = l * f + e;
        acc.x = acc.x * f + e * v4.x;
        acc.y = acc.y * f + e * v4.y;
        acc.z = acc.z * f + e * v4.z;
        acc.w = acc.w * f + e * v4.w;
        m = mn;
    }

    // combine the two halves of the wave (each lane ends holding the
    // wave-partial for its d-quad; lanes 0..31 commit to LDS)
    const float mo = __shfl_xor(m, 32, 64);
    const float M  = fmaxf(m, mo);
    const float f  = __expf(m - M);
    float lw = l * f;
    lw += __shfl_xor(lw, 32, 64);
    float ax = acc.x * f, ay = acc.y * f, az = acc.z * f, aw = acc.w * f;
    ax += __shfl_xor(ax, 32, 64);
    ay += __shfl_xor(ay, 32, 64);
    az += __shfl_xor(az, 32, 64);
    aw += __shfl_xor(aw, 32, 64);
    if (half == 0) {
        ((float4*)(wo + w * D))[l32] = make_float4(ax, ay, az, aw);
        if (l32 == 0) { wm[w] = M; wl[w] = lw; }
    }
    __syncthreads();

    // coalesced raw-score dump: 256 threads, 256 floats
    out_scores[(size_t)b * NROWS + n0 + tid] = s_sc[tid];

    // combine 4 wave partials -> chunk partial
    if (tid < D) {
        const float Mx = fmaxf(fmaxf(wm[0], wm[1]), fmaxf(wm[2], wm[3]));
        const float r0 = __expf(wm[0] - Mx);
        const float r1 = __expf(wm[1] - Mx);
        const float r2 = __expf(wm[2] - Mx);
        const float r3 = __expf(wm[3] - Mx);
        const float o = wo[0 * D + tid] * r0 + wo[1 * D + tid] * r1 +
                        wo[2 * D + tid] * r2 + wo[3 * D + tid] * r3;
        part_o[(size_t)blockIdx.x * D + tid] = o;
        if (tid == 0) {
            part_m[blockIdx.x] = Mx;
            part_l[blockIdx.x] = wl[0] * r0 + wl[1] * r1 + wl[2] * r2 + wl[3] * r3;
        }
    }
}

// ---------------------------------------------------------------------------
// K2: one block per batch (128 threads = one per output dim). Combine the 32
// chunk partials -> global M, L, write context, stash M and 1/L for K3.
// ---------------------------------------------------------------------------
__global__ __launch_bounds__(128) void attend_k2(
    const float* __restrict__ part_m,
    const float* __restrict__ part_l,
    const float* __restrict__ part_o,
    float* __restrict__ out_ctx,        // d_out + B*N, [B, D]
    float* __restrict__ bM,
    float* __restrict__ bInvL)
{
    const int b = blockIdx.x;
    const int d = threadIdx.x;
    __shared__ float sm[NCHUNK], sl[NCHUNK];
    if (d < NCHUNK) {
        sm[d] = part_m[b * NCHUNK + d];
        sl[d] = part_l[b * NCHUNK + d];
    }
    __syncthreads();

    float M = -INFINITY;
    #pragma unroll
    for (int c = 0; c < NCHUNK; ++c) M = fmaxf(M, sm[c]);

    float L = 0.f, o = 0.f;
    #pragma unroll
    for (int c = 0; c < NCHUNK; ++c) {
        const float r = __expf(sm[c] - M);
        L += sl[c] * r;
        o += part_o[(size_t)(b * NCHUNK + c) * D + d] * r;
    }
    out_ctx[b * D + d] = o / L;
    if (d == 0) { bM[b] = M; bInvL[b] = 1.0f / L; }
}

// ---------------------------------------------------------------------------
// K3: finalize attn in place: attn = exp(s - M) * invL.
// ---------------------------------------------------------------------------
__global__ __launch_bounds__(256) void attend_k3(
    float* __restrict__ attn,           // d_out, [B, N] (holds raw scores)
    const float* __restrict__ bM,
    const float* __restrict__ bInvL)
{
    const int idx = blockIdx.x * 256 + threadIdx.x;
    const int b   = idx >> 13;          // / NROWS
    const float s = attn[idx];
    attn[idx] = __expf(s - bM[b]) * bInvL[b];
}

extern "C" void kernel_launch(void* const* d_in, const int* in_sizes, int n_in,
                              void* d_out, int out_size, void* d_ws, size_t ws_size,
                              hipStream_t stream) {
    const float* q = (const float*)d_in[0];   // [B,1,D]
    const float* v = (const float*)d_in[1];   // [B,N,D]
    float* out = (float*)d_out;               // attn [B*N] then context [B*D]

    // workspace (floats):
    //   part_m [B*NCHUNK] | part_l [B*NCHUNK] | part_o [B*NCHUNK*D] | bM [B] | bInvL [B]
    float* ws      = (float*)d_ws;
    float* part_m  = ws;
    float* part_l  = part_m + B * NCHUNK;
    float* part_o  = part_l + B * NCHUNK;
    float* bM      = part_o + (size_t)B * NCHUNK * D;
    float* bInvL   = bM + B;

    attend_k1<<<B * NCHUNK, 256, 0, stream>>>(q, v, out, part_m, part_l, part_o);
    attend_k2<<<B, 128, 0, stream>>>(part_m, part_l, part_o, out + (size_t)B * NROWS, bM, bInvL);
    attend_k3<<<(B * NROWS) / 256, 256, 0, stream>>>(out, bM, bInvL);
}